// Round 1
// baseline (627.656 us; speedup 1.0000x reference)
//
#include <hip/hip_runtime.h>
#include <hip/hip_bf16.h>

#define B_ 256
#define T_ 512
#define V_ 30000
#define E_ 256
#define H_ 32

// ---------------------------------------------------------------------------
// Fast activations (fp32, monotone-safe at extremes: no NaN, saturate to 0/1/±1)
// ---------------------------------------------------------------------------
__device__ __forceinline__ float sigmoidf_fast(float x) {
    return 1.0f / (1.0f + __expf(-x));
}
__device__ __forceinline__ float tanhf_fast(float x) {
    // 1 - 2/(1+exp(2x)); exp overflow -> inf -> result 1; underflow -> -1
    return 1.0f - 2.0f / (1.0f + __expf(2.0f * x));
}
__device__ __forceinline__ float rl(float v, int lane) {
    return __int_as_float(__builtin_amdgcn_readlane(__float_as_int(v), lane));
}

// ---------------------------------------------------------------------------
// GEMM: Out[M,192] = A[M,K] @ Wcat[192,K]^T + bias
//   Wcat rows 0..95 = Wf (gates r,z,n), 96..191 = Wb
//   bias folds bih (all gates) + bhh (r,z only; n's bhh stays in the scan)
// Tile: 64(M) x 192(N), K-chunks of 32. 256 threads, each computes 8x6.
// ---------------------------------------------------------------------------
#define GEMM_MT 64
#define GEMM_KC 32
#define GEMM_PA 68
#define GEMM_PB 196

__global__ __launch_bounds__(256) void gemm_gates(
    const float* __restrict__ A, int M, int K,
    const float* __restrict__ Wf, const float* __restrict__ Wb,
    const float* __restrict__ bihf, const float* __restrict__ bhhf,
    const float* __restrict__ bihb, const float* __restrict__ bhhb,
    float* __restrict__ Out)
{
    __shared__ float As[GEMM_KC][GEMM_PA];   // k-major, padded
    __shared__ float Bs[GEMM_KC][GEMM_PB];

    const int tid = threadIdx.x;
    const int mbase = blockIdx.x * GEMM_MT;
    const int mg = tid >> 5, ng = tid & 31;
    const int m_off = mg * 8, n_off = ng * 6;

    float acc[8][6];
    #pragma unroll
    for (int r = 0; r < 8; ++r)
        #pragma unroll
        for (int c = 0; c < 6; ++c) acc[r][c] = 0.f;

    for (int kc = 0; kc < K; kc += GEMM_KC) {
        // A tile: 64 rows x 32 cols = 512 float4, transposed into LDS
        #pragma unroll
        for (int i = 0; i < 2; ++i) {
            int fi = tid + 256 * i;
            int row = fi >> 3, cf = fi & 7;
            int m = mbase + row;
            float4 v = make_float4(0.f, 0.f, 0.f, 0.f);
            if (m < M) v = *(const float4*)&A[(size_t)m * K + kc + cf * 4];
            As[cf * 4 + 0][row] = v.x; As[cf * 4 + 1][row] = v.y;
            As[cf * 4 + 2][row] = v.z; As[cf * 4 + 3][row] = v.w;
        }
        // B tile: 192 rows x 32 cols = 1536 float4
        #pragma unroll
        for (int i = 0; i < 6; ++i) {
            int fi = tid + 256 * i;
            int g = fi >> 3, cf = fi & 7;
            const float* Wsel = (g < 96) ? (Wf + (size_t)g * K)
                                         : (Wb + (size_t)(g - 96) * K);
            float4 v = *(const float4*)&Wsel[kc + cf * 4];
            Bs[cf * 4 + 0][g] = v.x; Bs[cf * 4 + 1][g] = v.y;
            Bs[cf * 4 + 2][g] = v.z; Bs[cf * 4 + 3][g] = v.w;
        }
        __syncthreads();
        #pragma unroll
        for (int k = 0; k < GEMM_KC; ++k) {
            float a[8], bb[6];
            *(float4*)&a[0] = *(const float4*)&As[k][m_off];
            *(float4*)&a[4] = *(const float4*)&As[k][m_off + 4];
            *(float2*)&bb[0] = *(const float2*)&Bs[k][n_off];
            *(float2*)&bb[2] = *(const float2*)&Bs[k][n_off + 2];
            *(float2*)&bb[4] = *(const float2*)&Bs[k][n_off + 4];
            #pragma unroll
            for (int r = 0; r < 8; ++r)
                #pragma unroll
                for (int c = 0; c < 6; ++c)
                    acc[r][c] = fmaf(a[r], bb[c], acc[r][c]);
        }
        __syncthreads();
    }

    float bias[6];
    #pragma unroll
    for (int c = 0; c < 6; ++c) {
        int g = n_off + c;
        int g96 = (g < 96) ? g : g - 96;
        const float* bih = (g < 96) ? bihf : bihb;
        const float* bhh = (g < 96) ? bhhf : bhhb;
        bias[c] = bih[g96] + ((g96 < 64) ? bhh[g96] : 0.f);
    }
    #pragma unroll
    for (int r = 0; r < 8; ++r) {
        int m = mbase + m_off + r;
        if (m < M) {
            float* op = &Out[(size_t)m * 192 + n_off];
            #pragma unroll
            for (int c = 0; c < 6; ++c) op[c] = acc[r][c] + bias[c];
        }
    }
}

// ---------------------------------------------------------------------------
// GRU scan: one wave (64 lanes) per (batch, direction) sequence.
//   h[j] lives in lane j (j<32). Broadcast via v_readlane -> no LDS, no barrier.
//   Lane l<32 : computes gh_r[j] and gh_n[j]  (wA = Whh row r_j, wB = row n_j)
//   Lane l>=32: computes gh_z[j]              (wA = Whh row z_j)
//   gi rows (192 wide: dir f 0..95, dir b 96..191) already contain
//   bih (all gates) + bhh (r,z). bhh_n is added to hn before r*hn.
// ---------------------------------------------------------------------------
__global__ __launch_bounds__(64) void gru_scan(
    const float* __restrict__ gi,     // [rows,192]: G0 gather or gi1 direct
    const int* __restrict__ ids,      // used when use_ids != 0
    const int* __restrict__ mask,     // [B,T] int
    const float* __restrict__ Whh_f, const float* __restrict__ Whh_b,
    const float* __restrict__ bhh_f, const float* __restrict__ bhh_b,
    float* __restrict__ out_seq,      // [B,T,64] or nullptr
    float* __restrict__ out_fin,      // [B,64]   or nullptr
    int use_ids)
{
    const int l = threadIdx.x;
    const int j = l & 31;
    const bool lower = l < 32;
    const int dir = blockIdx.x & 1;
    const int b = blockIdx.x >> 1;
    const int bT = b * T_;

    const float* Whh = dir ? Whh_b : Whh_f;
    const float* bhh = dir ? bhh_b : bhh_f;

    const int rowA = lower ? j : (32 + j);  // r-row (lower) / z-row (upper)
    const int rowB = 64 + j;                // n-row (meaningful for lower)
    float wA[32], wB[32];
    #pragma unroll
    for (int k = 0; k < 32; ++k) {
        wA[k] = Whh[rowA * 32 + k];
        wB[k] = Whh[rowB * 32 + k];
    }
    const float bn = bhh[64 + j];

    float h = 0.f;
    int t = dir ? (T_ - 1) : 0;
    const int dt = dir ? -1 : 1;

    // prologue load for first step
    int row = use_ids ? ids[bT + t] : (bT + t);
    int m = mask[bT + t];
    {
        const float* gp = gi + (size_t)row * 192 + dir * 96;
        // (loads issued below via gA/gB init)
    }
    const float* gp0 = gi + (size_t)row * 192 + dir * 96;
    float gA = gp0[l];        // r (lower) / z (upper) input+bias
    float gB = gp0[64 + j];   // n input (+bih_n)

    for (int i = 0; i < T_; ++i) {
        const int tn = t + dt;
        float gA_n = 0.f, gB_n = 0.f;
        int m_n = 0;
        if (i + 1 < T_) {   // prefetch next step's inputs
            int row_n = use_ids ? ids[bT + tn] : (bT + tn);
            m_n = mask[bT + tn];
            const float* gp = gi + (size_t)row_n * 192 + dir * 96;
            gA_n = gp[l];
            gB_n = gp[64 + j];
        }

        // recurrent matvec via readlane broadcast; 2 accumulators/gate to
        // shorten the dependent-FMA chain
        float aA0 = 0.f, aA1 = 0.f, aB0 = 0.f, aB1 = 0.f;
        #pragma unroll
        for (int k = 0; k < 32; k += 2) {
            const float h0 = rl(h, k);
            const float h1 = rl(h, k + 1);
            aA0 = fmaf(wA[k],     h0, aA0);
            aB0 = fmaf(wB[k],     h0, aB0);
            aA1 = fmaf(wA[k + 1], h1, aA1);
            aB1 = fmaf(wB[k + 1], h1, aB1);
        }

        const float s  = sigmoidf_fast(gA + aA0 + aA1); // r (lower) / z (upper)
        const float hn = bn + aB0 + aB1;                // h·Whh_n + bhh_n
        const float zz = __shfl_xor(s, 32, 64);         // lower lanes receive z
        const float n  = tanhf_fast(gB + s * hn);       // lower: s == r
        const float hnew = n + zz * (h - n);            // (1-z)n + z h
        h = m ? hnew : h;                               // packed-seq freeze

        if (out_seq != nullptr && lower)
            out_seq[((size_t)(bT + t)) * 64 + dir * 32 + j] = h;

        gA = gA_n; gB = gB_n; m = m_n; t = tn;
    }

    if (out_fin != nullptr && lower)
        out_fin[b * 64 + dir * 32 + j] = h;
}

// ---------------------------------------------------------------------------
// Head: out[b,o] = hfin[b,:] . Wout[o,:] + bout[o]   (tiny)
// ---------------------------------------------------------------------------
__global__ void head_kernel(const float* __restrict__ hfin,
                            const float* __restrict__ Wout,
                            const float* __restrict__ bout,
                            float* __restrict__ out)
{
    int idx = blockIdx.x * blockDim.x + threadIdx.x;
    if (idx >= B_ * 6) return;
    int b = idx / 6, o = idx % 6;
    float acc = bout[o];
    const float* hp = hfin + b * 64;
    const float* wp = Wout + o * 64;
    #pragma unroll
    for (int k = 0; k < 64; ++k) acc = fmaf(hp[k], wp[k], acc);
    out[idx] = acc;
}

// ---------------------------------------------------------------------------
extern "C" void kernel_launch(void* const* d_in, const int* in_sizes, int n_in,
                              void* d_out, int out_size, void* d_ws, size_t ws_size,
                              hipStream_t stream)
{
    const int*   ids   = (const int*)d_in[0];
    const int*   mask  = (const int*)d_in[1];
    const float* embed = (const float*)d_in[2];
    const float* Wih0f = (const float*)d_in[3];
    const float* Whh0f = (const float*)d_in[4];
    const float* bih0f = (const float*)d_in[5];
    const float* bhh0f = (const float*)d_in[6];
    const float* Wih0b = (const float*)d_in[7];
    const float* Whh0b = (const float*)d_in[8];
    const float* bih0b = (const float*)d_in[9];
    const float* bhh0b = (const float*)d_in[10];
    const float* Wih1f = (const float*)d_in[11];
    const float* Whh1f = (const float*)d_in[12];
    const float* bih1f = (const float*)d_in[13];
    const float* bhh1f = (const float*)d_in[14];
    const float* Wih1b = (const float*)d_in[15];
    const float* Whh1b = (const float*)d_in[16];
    const float* bih1b = (const float*)d_in[17];
    const float* bhh1b = (const float*)d_in[18];
    const float* Wout  = (const float*)d_in[19];
    const float* bout  = (const float*)d_in[20];

    // workspace layout (floats):
    //   [0, 25165824)              gbuf : G0 [V,192] (K1,K2) then gi1 [B*T,192] (K3,K4)
    //   [25165824, 33554432)       x1   : [B,T,64]
    //   [33554432, 33570816)       hfin : [B,64]
    float* ws   = (float*)d_ws;
    float* gbuf = ws;
    float* x1   = ws + (size_t)B_ * T_ * 192;
    float* hfin = x1 + (size_t)B_ * T_ * 64;

    // K1: vocab-factored layer-0 input gates  G0 = embed @ Wcat0^T + bias
    gemm_gates<<<(V_ + GEMM_MT - 1) / GEMM_MT, 256, 0, stream>>>(
        embed, V_, E_, Wih0f, Wih0b, bih0f, bhh0f, bih0b, bhh0b, gbuf);

    // K2: layer-0 bidirectional scan (gathers G0[id]), writes x1
    gru_scan<<<2 * B_, 64, 0, stream>>>(
        gbuf, ids, mask, Whh0f, Whh0b, bhh0f, bhh0b, x1, nullptr, 1);

    // K3: layer-1 input gates  gi1 = x1 @ Wcat1^T + bias  (overwrites dead G0)
    gemm_gates<<<(B_ * T_) / GEMM_MT, 256, 0, stream>>>(
        x1, B_ * T_, 64, Wih1f, Wih1b, bih1f, bhh1f, bih1b, bhh1b, gbuf);

    // K4: layer-1 scan, final hiddens only
    gru_scan<<<2 * B_, 64, 0, stream>>>(
        gbuf, nullptr, mask, Whh1f, Whh1b, bhh1f, bhh1b, nullptr, hfin, 0);

    // K5: output head
    head_kernel<<<(B_ * 6 + 255) / 256, 256, 0, stream>>>(hfin, Wout, bout,
                                                          (float*)d_out);
}